// Round 1
// baseline (1951.286 us; speedup 1.0000x reference)
//
#include <hip/hip_runtime.h>
#include <hip/hip_bf16.h>

// Problem constants (RGCN encoder): N=100000 nodes, E=128, R=9, L=3, NE=640000.
// Only the LAST layer matters (reference resets hidden=embeddings each layer).
#define E_DIM 128
#define R_REL 9

#define BM 64
#define BK 32

// ht[r] = H @ W_r  for r = blockIdx.y, with configurable relation strides so the
// same kernel serves the "all 18 relations" path and the "pair (r, r+9)" path.
__global__ __launch_bounds__(256) void gemm_ht(
    const float* __restrict__ H,    // [Nn][128]
    const float* __restrict__ W0,   // base of first relation's [128][128]
    size_t wstride,                 // elements between consecutive relations
    float* __restrict__ ht0,        // base of first relation's [Nn][128] output
    size_t hstride,                 // elements between consecutive ht outputs
    int Nn)
{
    __shared__ float Hs[BK][BM];        // transposed: Hs[k][n]
    __shared__ float Ws[BK][E_DIM];

    const int r = blockIdx.y;
    const float* __restrict__ Wr = W0 + (size_t)r * wstride;
    float* __restrict__ htr = ht0 + (size_t)r * hstride;

    const int n0 = blockIdx.x * BM;
    const int tid = threadIdx.x;
    const int tx = tid & 15;        // col group: cols tx*8 .. tx*8+7
    const int ty = tid >> 4;        // row group: rows ty*4 .. ty*4+3

    float acc[4][8];
#pragma unroll
    for (int i = 0; i < 4; i++)
#pragma unroll
        for (int j = 0; j < 8; j++) acc[i][j] = 0.f;

    for (int k0 = 0; k0 < E_DIM; k0 += BK) {
        // Stage H tile (64 rows x 32 k) transposed into Hs[k][n].
#pragma unroll
        for (int l = 0; l < 2; l++) {
            int idx = tid + l * 256;          // 0..511 float4 slots
            int rr = idx >> 3;                // 0..63
            int cc = (idx & 7) * 4;           // 0..28
            int n = n0 + rr;
            float4 v = make_float4(0.f, 0.f, 0.f, 0.f);
            if (n < Nn) v = *(const float4*)(H + (size_t)n * E_DIM + k0 + cc);
            Hs[cc + 0][rr] = v.x;
            Hs[cc + 1][rr] = v.y;
            Hs[cc + 2][rr] = v.z;
            Hs[cc + 3][rr] = v.w;
        }
        // Stage W tile (32 k x 128 cols) as-is.
#pragma unroll
        for (int l = 0; l < 4; l++) {
            int idx = tid + l * 256;          // 0..1023 float4 slots
            int kk = idx >> 5;                // 0..31
            int cc = (idx & 31) * 4;          // 0..124
            *(float4*)(&Ws[kk][cc]) = *(const float4*)(Wr + (size_t)(k0 + kk) * E_DIM + cc);
        }
        __syncthreads();

#pragma unroll
        for (int k = 0; k < BK; k++) {
            float4 a = *(const float4*)(&Hs[k][ty * 4]);
            float4 b0 = *(const float4*)(&Ws[k][tx * 8]);
            float4 b1 = *(const float4*)(&Ws[k][tx * 8 + 4]);
            float av[4] = {a.x, a.y, a.z, a.w};
            float bv[8] = {b0.x, b0.y, b0.z, b0.w, b1.x, b1.y, b1.z, b1.w};
#pragma unroll
            for (int i = 0; i < 4; i++)
#pragma unroll
                for (int j = 0; j < 8; j++) acc[i][j] += av[i] * bv[j];
        }
        __syncthreads();
    }

#pragma unroll
    for (int i = 0; i < 4; i++) {
        int n = n0 + ty * 4 + i;
        if (n < Nn) {
            float4 o0 = make_float4(acc[i][0], acc[i][1], acc[i][2], acc[i][3]);
            float4 o1 = make_float4(acc[i][4], acc[i][5], acc[i][6], acc[i][7]);
            *(float4*)(htr + (size_t)n * E_DIM + tx * 8) = o0;
            *(float4*)(htr + (size_t)n * E_DIM + tx * 8 + 4) = o1;
        }
    }
}

// Full path: ht holds all 18 relations [18][Nn][128]. One wave per edge,
// each lane handles 2 channels (float2 -> coalesced 512B per gather).
__global__ __launch_bounds__(256) void scatter_full(
    const int* __restrict__ esrc, const int* __restrict__ edst,
    const int* __restrict__ etype,
    const float* __restrict__ ht,       // [18][Nn][128]
    const float* __restrict__ B2,       // [18][128]
    float* __restrict__ out, int ne, int Nn)
{
    int wid = blockIdx.x * 4 + (threadIdx.x >> 6);
    if (wid >= ne) return;
    int lane = threadIdx.x & 63;
    int t = etype[wid];
    int s = esrc[wid];
    int d = edst[wid];

    const float2* vf = (const float2*)(ht + ((size_t)t * Nn + s) * E_DIM);
    const float2* vb = (const float2*)(ht + ((size_t)(t + R_REL) * Nn + d) * E_DIM);
    const float2* bf = (const float2*)(B2 + (size_t)t * E_DIM);
    const float2* bb = (const float2*)(B2 + (size_t)(t + R_REL) * E_DIM);

    float2 a = vf[lane], af = bf[lane];
    float2 c = vb[lane], cb = bb[lane];

    float* od = out + (size_t)d * E_DIM + 2 * lane;
    float* os = out + (size_t)s * E_DIM + 2 * lane;
    atomicAdd(od + 0, a.x + af.x);
    atomicAdd(od + 1, a.y + af.y);
    atomicAdd(os + 0, c.x + cb.x);
    atomicAdd(os + 1, c.y + cb.y);
}

// Pair path: ht_f = ws, ht_b = ws + Nn*128; only edges of type==r are handled.
__global__ __launch_bounds__(256) void scatter_pair(
    const int* __restrict__ esrc, const int* __restrict__ edst,
    const int* __restrict__ etype,
    const float* __restrict__ ht_f, const float* __restrict__ ht_b,
    const float* __restrict__ B2,
    float* __restrict__ out, int ne, int Nn, int r)
{
    int wid = blockIdx.x * 4 + (threadIdx.x >> 6);
    if (wid >= ne) return;
    if (etype[wid] != r) return;
    int lane = threadIdx.x & 63;
    int s = esrc[wid];
    int d = edst[wid];

    const float2* vf = (const float2*)(ht_f + (size_t)s * E_DIM);
    const float2* vb = (const float2*)(ht_b + (size_t)d * E_DIM);
    const float2* bf = (const float2*)(B2 + (size_t)r * E_DIM);
    const float2* bb = (const float2*)(B2 + (size_t)(r + R_REL) * E_DIM);

    float2 a = vf[lane], af = bf[lane];
    float2 c = vb[lane], cb = bb[lane];

    float* od = out + (size_t)d * E_DIM + 2 * lane;
    float* os = out + (size_t)s * E_DIM + 2 * lane;
    atomicAdd(od + 0, a.x + af.x);
    atomicAdd(od + 1, a.y + af.y);
    atomicAdd(os + 0, c.x + cb.x);
    atomicAdd(os + 1, c.y + cb.y);
}

// Zero-workspace fallback: direct per-edge GEMV (one 128-thread block per edge).
__global__ __launch_bounds__(128) void direct_edge(
    const int* __restrict__ esrc, const int* __restrict__ edst,
    const int* __restrict__ etype,
    const float* __restrict__ H, const float* __restrict__ W2,
    const float* __restrict__ B2, float* __restrict__ out, int ne)
{
    __shared__ float hs[E_DIM];
    __shared__ float hd[E_DIM];
    int e = blockIdx.x;
    if (e >= ne) return;
    int t = etype[e], s = esrc[e], d = edst[e];
    int c = threadIdx.x;
    hs[c] = H[(size_t)s * E_DIM + c];
    hd[c] = H[(size_t)d * E_DIM + c];
    __syncthreads();
    const float* Wf = W2 + (size_t)t * E_DIM * E_DIM;
    const float* Wb = W2 + (size_t)(t + R_REL) * E_DIM * E_DIM;
    float accf = B2[(size_t)t * E_DIM + c];
    float accb = B2[(size_t)(t + R_REL) * E_DIM + c];
#pragma unroll 8
    for (int k = 0; k < E_DIM; k++) {
        accf += hs[k] * Wf[(size_t)k * E_DIM + c];
        accb += hd[k] * Wb[(size_t)k * E_DIM + c];
    }
    atomicAdd(&out[(size_t)d * E_DIM + c], accf);
    atomicAdd(&out[(size_t)s * E_DIM + c], accb);
}

extern "C" void kernel_launch(void* const* d_in, const int* in_sizes, int n_in,
                              void* d_out, int out_size, void* d_ws, size_t ws_size,
                              hipStream_t stream) {
    const int* edge_index = (const int*)d_in[0];   // [2][NE]
    const int* edge_type  = (const int*)d_in[1];   // [NE]
    const float* emb      = (const float*)d_in[2]; // [N][128]
    const float* weights  = (const float*)d_in[3]; // [L][18][128][128]
    const float* biases   = (const float*)d_in[4]; // [L][18][128]
    float* out = (float*)d_out;

    const int NE = in_sizes[1];
    const int Nn = in_sizes[2] / E_DIM;
    const int L  = in_sizes[3] / (2 * R_REL * E_DIM * E_DIM);

    const float* W2 = weights + (size_t)(L - 1) * 2 * R_REL * E_DIM * E_DIM;
    const float* B2 = biases  + (size_t)(L - 1) * 2 * R_REL * E_DIM;

    const int* esrc = edge_index;
    const int* edst = edge_index + NE;

    const size_t out_bytes = (size_t)Nn * E_DIM * sizeof(float);
    const size_t ht_one = (size_t)Nn * E_DIM * sizeof(float);

    hipMemsetAsync(d_out, 0, out_bytes, stream);

    const int gemm_gx = (Nn + BM - 1) / BM;

    if (ws_size >= 18 * ht_one) {
        // Full path: all 18 ht matrices, single scatter pass.
        float* ht = (float*)d_ws;
        dim3 g1(gemm_gx, 18);
        gemm_ht<<<g1, 256, 0, stream>>>(emb, W2, (size_t)E_DIM * E_DIM,
                                        ht, (size_t)Nn * E_DIM, Nn);
        scatter_full<<<(NE + 3) / 4, 256, 0, stream>>>(
            esrc, edst, edge_type, ht, B2, out, NE, Nn);
    } else if (ws_size >= 2 * ht_one) {
        // Pair path: 9 passes of (forward r, backward r+9).
        float* ht_f = (float*)d_ws;
        float* ht_b = ht_f + (size_t)Nn * E_DIM;
        for (int r = 0; r < R_REL; r++) {
            dim3 g1(gemm_gx, 2);
            gemm_ht<<<g1, 256, 0, stream>>>(
                emb, W2 + (size_t)r * E_DIM * E_DIM,
                (size_t)R_REL * E_DIM * E_DIM,
                ht_f, (size_t)Nn * E_DIM, Nn);
            scatter_pair<<<(NE + 3) / 4, 256, 0, stream>>>(
                esrc, edst, edge_type, ht_f, ht_b, B2, out, NE, Nn, r);
        }
    } else {
        // Zero-workspace fallback: direct per-edge GEMV.
        direct_edge<<<NE, 128, 0, stream>>>(esrc, edst, edge_type, emb, W2, B2, out, NE);
    }
}

// Round 2
// 1279.332 us; speedup vs baseline: 1.5252x; 1.5252x over previous
//
#include <hip/hip_runtime.h>
#include <hip/hip_bf16.h>

// RGCN encoder: N=100000 nodes, E=128, R=9, L=3, NE=640000.
// Only the LAST layer matters (reference resets hidden=embeddings per layer).
//   out[n] = sum_{e:dst=n} (W_t h[src] + b_t) + sum_{e:src=n} (W_{t+9} h[dst] + b_{t+9})
// Strategy: ht[r] = H*W_r + b_r (bf16, MFMA), then one wave per edge gathers
// and atomically scatters fp32 into out. Relations processed in groups sized
// by ws_size (bf16 buffers are 25.6 MB each).

#define E_DIM 128
#define R_REL 9
#define GBM 64

typedef __attribute__((ext_vector_type(8))) short short8v;
typedef __attribute__((ext_vector_type(4))) float f32x4;

static __device__ __forceinline__ unsigned short f2bf(float f) {
    union { float f; unsigned u; } v; v.f = f;
    unsigned u = v.u;
    return (unsigned short)((u + 0x7FFFu + ((u >> 16) & 1u)) >> 16);
}
static __device__ __forceinline__ float bf2f(unsigned short h) {
    union { unsigned u; float f; } v; v.u = ((unsigned)h) << 16;
    return v.f;
}

// ht[buffer b] = H @ W_rel + b_rel (bf16 out), rel = p0 + (b>>1) + (b&1 ? 9 : 0).
// 256 thr = 4 waves; block tile 64 rows x 128 cols; wave owns a 64x32 col
// slice (4 row-frags x 2 col-frags, K=128 in 4 MFMA steps). B-frags register-
// resident across a grid-stride row loop.
__global__ __launch_bounds__(256) void gemm_bf16(
    const float* __restrict__ H, const float* __restrict__ W18,
    const float* __restrict__ B18, unsigned short* __restrict__ htB,
    size_t bufstride, int p0, int Nn)
{
    __shared__ __align__(16) unsigned short As[GBM][136];  // +8 pad: conflict-free b128

    const int b = blockIdx.y;
    const int rel = p0 + (b >> 1) + ((b & 1) ? R_REL : 0);
    const float* __restrict__ Wr = W18 + (size_t)rel * E_DIM * E_DIM;
    unsigned short* __restrict__ ho = htB + (size_t)b * bufstride;

    const int tid = threadIdx.x;
    const int lane = tid & 63;
    const int wc = (tid >> 6) * 32;
    const int lr = lane & 15;
    const int lg = lane >> 4;

    // B-frags: b[s][c][j] = W[s*32+lg*8+j][wc+c*16+lr]  (fp32 -> bf16)
    short8v bfrag[4][2];
#pragma unroll
    for (int s = 0; s < 4; s++)
#pragma unroll
        for (int c = 0; c < 2; c++) {
#pragma unroll
            for (int j = 0; j < 8; j++) {
                float w = Wr[(size_t)(s * 32 + lg * 8 + j) * E_DIM + wc + c * 16 + lr];
                bfrag[s][c][j] = (short)f2bf(w);
            }
        }
    const float bias0 = B18[(size_t)rel * E_DIM + wc + lr];
    const float bias1 = B18[(size_t)rel * E_DIM + wc + 16 + lr];

    const int ntiles = (Nn + GBM - 1) / GBM;
    for (int rt = blockIdx.x; rt < ntiles; rt += gridDim.x) {
        const int n0 = rt * GBM;

        // Stage A tile: 64 rows x 128 k, fp32 -> bf16, coalesced float4 reads.
#pragma unroll
        for (int j = 0; j < 8; j++) {
            int i = tid + j * 256;            // 0..2047 float4 slots
            int row = i >> 5;                 // 32 float4 per row
            int c4 = (i & 31) * 4;
            int n = n0 + row;
            float4 v = make_float4(0.f, 0.f, 0.f, 0.f);
            if (n < Nn) v = *(const float4*)(H + (size_t)n * E_DIM + c4);
            ushort4 b4;
            b4.x = f2bf(v.x); b4.y = f2bf(v.y); b4.z = f2bf(v.z); b4.w = f2bf(v.w);
            *(ushort4*)(&As[row][c4]) = b4;
        }
        __syncthreads();

        f32x4 acc[4][2];
#pragma unroll
        for (int m = 0; m < 4; m++)
#pragma unroll
            for (int c = 0; c < 2; c++) acc[m][c] = (f32x4){0.f, 0.f, 0.f, 0.f};

#pragma unroll
        for (int s = 0; s < 4; s++) {
#pragma unroll
            for (int m = 0; m < 4; m++) {
                short8v a = *(const short8v*)(&As[m * 16 + lr][s * 32 + lg * 8]);
#pragma unroll
                for (int c = 0; c < 2; c++)
                    acc[m][c] = __builtin_amdgcn_mfma_f32_16x16x32_bf16(
                        a, bfrag[s][c], acc[m][c], 0, 0, 0);
            }
        }
        __syncthreads();  // done reading As; reuse as C staging

        // C frags (+bias) -> LDS bf16. D layout: col = lane&15, row = lg*4+q.
#pragma unroll
        for (int m = 0; m < 4; m++)
#pragma unroll
            for (int c = 0; c < 2; c++) {
                float bias = c ? bias1 : bias0;
#pragma unroll
                for (int q = 0; q < 4; q++)
                    As[m * 16 + lg * 4 + q][wc + c * 16 + lr] = f2bf(acc[m][c][q] + bias);
            }
        __syncthreads();

        // Coalesced LDS -> global bf16 copy.
#pragma unroll
        for (int j = 0; j < 4; j++) {
            int i = tid + j * 256;            // 0..1023 16B chunks
            int row = i >> 4;
            int c8 = (i & 15) * 8;
            int n = n0 + row;
            if (n < Nn) {
                short8v v = *(const short8v*)(&As[row][c8]);
                *(short8v*)(ho + (size_t)n * E_DIM + c8) = v;
            }
        }
        __syncthreads();  // before next iteration overwrites As
    }
}

// One wave per edge; lane handles 2 channels. Bias already folded into ht.
// Buffer 2q = forward rel p0+q (gather src, scatter dst);
// buffer 2q+1 = backward rel p0+q+9 (gather dst, scatter src).
__global__ __launch_bounds__(256) void scatter_grp(
    const int* __restrict__ esrc, const int* __restrict__ edst,
    const int* __restrict__ etype,
    const unsigned short* __restrict__ htB, size_t bufstride,
    float* __restrict__ out, int ne, int p0, int pg)
{
    int wid = blockIdx.x * 4 + (threadIdx.x >> 6);
    if (wid >= ne) return;
    int t = etype[wid];
    int q = t - p0;
    if ((unsigned)q >= (unsigned)pg) return;
    int lane = threadIdx.x & 63;
    int s = esrc[wid], d = edst[wid];

    const ushort2* vf = (const ushort2*)(htB + (size_t)(2 * q) * bufstride + (size_t)s * E_DIM);
    const ushort2* vb = (const ushort2*)(htB + (size_t)(2 * q + 1) * bufstride + (size_t)d * E_DIM);
    ushort2 a = vf[lane];
    ushort2 c = vb[lane];

    float* od = out + (size_t)d * E_DIM + 2 * lane;
    float* os = out + (size_t)s * E_DIM + 2 * lane;
    atomicAdd(od + 0, bf2f(a.x));
    atomicAdd(od + 1, bf2f(a.y));
    atomicAdd(os + 0, bf2f(c.x));
    atomicAdd(os + 1, bf2f(c.y));
}

// Zero-workspace fallback: direct per-edge GEMV.
__global__ __launch_bounds__(128) void direct_edge(
    const int* __restrict__ esrc, const int* __restrict__ edst,
    const int* __restrict__ etype,
    const float* __restrict__ H, const float* __restrict__ W2,
    const float* __restrict__ B2, float* __restrict__ out, int ne)
{
    __shared__ float hs[E_DIM];
    __shared__ float hd[E_DIM];
    int e = blockIdx.x;
    if (e >= ne) return;
    int t = etype[e], s = esrc[e], d = edst[e];
    int c = threadIdx.x;
    hs[c] = H[(size_t)s * E_DIM + c];
    hd[c] = H[(size_t)d * E_DIM + c];
    __syncthreads();
    const float* Wf = W2 + (size_t)t * E_DIM * E_DIM;
    const float* Wb = W2 + (size_t)(t + R_REL) * E_DIM * E_DIM;
    float accf = B2[(size_t)t * E_DIM + c];
    float accb = B2[(size_t)(t + R_REL) * E_DIM + c];
#pragma unroll 8
    for (int k = 0; k < E_DIM; k++) {
        accf += hs[k] * Wf[(size_t)k * E_DIM + c];
        accb += hd[k] * Wb[(size_t)k * E_DIM + c];
    }
    atomicAdd(&out[(size_t)d * E_DIM + c], accf);
    atomicAdd(&out[(size_t)s * E_DIM + c], accb);
}

extern "C" void kernel_launch(void* const* d_in, const int* in_sizes, int n_in,
                              void* d_out, int out_size, void* d_ws, size_t ws_size,
                              hipStream_t stream) {
    const int* edge_index = (const int*)d_in[0];   // [2][NE]
    const int* edge_type  = (const int*)d_in[1];   // [NE]
    const float* emb      = (const float*)d_in[2]; // [N][128]
    const float* weights  = (const float*)d_in[3]; // [L][18][128][128]
    const float* biases   = (const float*)d_in[4]; // [L][18][128]
    float* out = (float*)d_out;

    const int NE = in_sizes[1];
    const int Nn = in_sizes[2] / E_DIM;
    const int L  = in_sizes[3] / (2 * R_REL * E_DIM * E_DIM);

    const float* W2 = weights + (size_t)(L - 1) * 2 * R_REL * E_DIM * E_DIM;
    const float* B2 = biases  + (size_t)(L - 1) * 2 * R_REL * E_DIM;

    const int* esrc = edge_index;
    const int* edst = edge_index + NE;

    hipMemsetAsync(d_out, 0, (size_t)Nn * E_DIM * sizeof(float), stream);

    const size_t bufelems = (size_t)Nn * E_DIM;               // bf16 elements
    const size_t bufbytes = bufelems * sizeof(unsigned short);
    const int nbuf = (int)(ws_size / bufbytes);

    if (nbuf >= 2) {
        const int PG = (nbuf / 2 < R_REL) ? (nbuf / 2) : R_REL;
        unsigned short* htB = (unsigned short*)d_ws;
        const int gx = (Nn + GBM * 4 - 1) / (GBM * 4);        // ~4 row-tiles/block
        for (int p0 = 0; p0 < R_REL; ) {
            int pg = (R_REL - p0 < PG) ? (R_REL - p0) : PG;
            dim3 g1(gx, 2 * pg);
            gemm_bf16<<<g1, 256, 0, stream>>>(emb, W2, B2, htB, bufelems, p0, Nn);
            scatter_grp<<<(NE + 3) / 4, 256, 0, stream>>>(
                esrc, edst, edge_type, htB, bufelems, out, NE, p0, pg);
            p0 += pg;
        }
    } else {
        direct_edge<<<NE, 128, 0, stream>>>(esrc, edst, edge_type, emb, W2, B2, out, NE);
    }
}